// Round 4
// baseline (629.919 us; speedup 1.0000x reference)
//
#include <hip/hip_runtime.h>
#include <math.h>

#define DIM 128
#define CHUNK 4
#define STREAMS 8          // half-wave node-streams per 256-thread block
#define STRIDE (STREAMS)   // node stride between a stream's consecutive nodes
#define ROUND (STREAMS * CHUNK)

typedef float v4f __attribute__((ext_vector_type(4)));

// lower_bound over sorted int array; all arguments are blockIdx-uniform so
// the compiler emits scalar loads.
__device__ __forceinline__ int lower_bound_i(const int* __restrict__ b, int n, int key) {
    int lo = 0, hi = n;
    while (lo < hi) {
        int mid = (lo + hi) >> 1;
        if (b[mid] < key) lo = mid + 1; else hi = mid;
    }
    return lo;
}

// One block per graph. 256 threads = 4 waves = 8 half-wave node-streams.
// Bulk loop does CHUNK nodes/round with no per-slot bounds checks (fewer live
// temps, one rescale per round); <=CHUNK-1 leftover nodes go through a scalar
// tail. __launch_bounds__(256,8) forces <=64 VGPR -> 32 waves/CU for latency
// coverage via TLP. x is streamed exactly once -> nontemporal loads.
__global__ __launch_bounds__(256, 8) void attnpool_kernel(
    const float* __restrict__ x, const float* __restrict__ q,
    const int* __restrict__ batch, float* __restrict__ out, int n)
{
    const int g    = blockIdx.x;
    const int tid  = threadIdx.x;
    const int wave = tid >> 6;
    const int lane = tid & 63;
    const int half = lane >> 5;   // 0 or 1
    const int hl   = lane & 31;   // lane within half
    const int sid  = wave * 2 + half;

    const int lo = lower_bound_i(batch, n, g);
    const int hi = lower_bound_i(batch, n, g + 1);

    // per-lane query fragment (dims hl*4 .. hl*4+3)
    const float4 qf = *(const float4*)(q + hl * 4);

    float  m = -INFINITY;
    float  l = 0.f;
    float4 o = make_float4(0.f, 0.f, 0.f, 0.f);

    const float* xb = x + hl * 4;
    int i = lo + sid;             // this stream's next node

    // ---- bulk: all CHUNK slots in-range, no predication ----
    while (i + (CHUNK - 1) * STRIDE < hi) {
        v4f cur[CHUNK];
        #pragma unroll
        for (int j = 0; j < CHUNK; ++j)
            cur[j] = __builtin_nontemporal_load((const v4f*)(xb + (size_t)(i + j * STRIDE) * DIM));

        float s[CHUNK];
        #pragma unroll
        for (int j = 0; j < CHUNK; ++j)
            s[j] = cur[j].x * qf.x + cur[j].y * qf.y + cur[j].z * qf.z + cur[j].w * qf.w;

        #pragma unroll
        for (int d = 16; d >= 1; d >>= 1) {
            #pragma unroll
            for (int j = 0; j < CHUNK; ++j)
                s[j] += __shfl_xor(s[j], d);
        }

        const float smax = fmaxf(fmaxf(s[0], s[1]), fmaxf(s[2], s[3]));
        if (smax > m) {   // m=-inf first round -> exp underflows to 0
            const float a = __expf(m - smax);
            l *= a;
            o.x *= a; o.y *= a; o.z *= a; o.w *= a;
            m = smax;
        }

        #pragma unroll
        for (int j = 0; j < CHUNK; ++j) {
            const float p = __expf(s[j] - m);
            l += p;
            o.x += p * cur[j].x; o.y += p * cur[j].y;
            o.z += p * cur[j].z; o.w += p * cur[j].w;
        }

        i += ROUND;
    }

    // ---- tail: up to CHUNK-1 nodes, branchy per-node update ----
    for (; i < hi; i += STRIDE) {
        const v4f xv = __builtin_nontemporal_load((const v4f*)(xb + (size_t)i * DIM));
        float s = xv.x * qf.x + xv.y * qf.y + xv.z * qf.z + xv.w * qf.w;
        #pragma unroll
        for (int d = 16; d >= 1; d >>= 1) s += __shfl_xor(s, d);
        if (s > m) {
            const float a = __expf(m - s);
            l = l * a + 1.f;
            o.x = o.x * a + xv.x; o.y = o.y * a + xv.y;
            o.z = o.z * a + xv.z; o.w = o.w * a + xv.w;
            m = s;
        } else {
            const float p = __expf(s - m);
            l += p;
            o.x += p * xv.x; o.y += p * xv.y;
            o.z += p * xv.z; o.w += p * xv.w;
        }
    }

    // ---- merge the 8 partial online-softmax states through LDS ----
    __shared__ float sm_m[STREAMS];
    __shared__ float sm_l[STREAMS];
    __shared__ float sm_o[STREAMS * DIM];
    if (hl == 0) { sm_m[sid] = m; sm_l[sid] = l; }
    *(float4*)(sm_o + sid * DIM + hl * 4) = make_float4(o.x, o.y, o.z, o.w);
    __syncthreads();

    if (tid < DIM) {
        float M = -INFINITY;
        #pragma unroll
        for (int h = 0; h < STREAMS; ++h)
            if (sm_l[h] > 0.f && sm_m[h] > M) M = sm_m[h];
        float L = 0.f, O = 0.f;
        #pragma unroll
        for (int h = 0; h < STREAMS; ++h) {
            if (sm_l[h] > 0.f) {
                const float c = __expf(sm_m[h] - M);
                L += c * sm_l[h];
                O += c * sm_o[h * DIM + tid];
            }
        }
        // empty segment -> L==0 -> write 0 (matches segment_sum identity)
        __builtin_nontemporal_store((L > 0.f) ? (O / L) : 0.f, out + (size_t)g * DIM + tid);
    }
}

extern "C" void kernel_launch(void* const* d_in, const int* in_sizes, int n_in,
                              void* d_out, int out_size, void* d_ws, size_t ws_size,
                              hipStream_t stream) {
    const float* x     = (const float*)d_in[0];
    const float* q     = (const float*)d_in[1];
    const int*   batch = (const int*)d_in[2];
    float*       out   = (float*)d_out;
    const int n          = in_sizes[0] / DIM;   // 1,000,000
    const int num_graphs = out_size / DIM;      // 4096
    attnpool_kernel<<<num_graphs, 256, 0, stream>>>(x, q, batch, out, n);
}